// Round 15
// baseline (168.461 us; speedup 1.0000x reference)
//
#include <hip/hip_runtime.h>
#include <hip/hip_bf16.h>
#include <hip/hip_cooperative_groups.h>

namespace cg = cooperative_groups;

// Problem constants (B,C,D,H,W = 2,64,16,16,16)
#define NB 2
#define NC 64
#define NS 4096   // D*H*W
#define KS 8      // key-split factor (across blocks)

typedef __attribute__((ext_vector_type(8))) short bf16x8;
typedef __attribute__((ext_vector_type(4))) short bf16x4;
typedef __attribute__((ext_vector_type(4))) float f32x4;
typedef __attribute__((ext_vector_type(4))) float float4v;
typedef __attribute__((ext_vector_type(4))) unsigned int u32x4;

static __device__ __forceinline__ short f2bf(float f) {
    union { float f; unsigned u; } c; c.f = f;
    unsigned r = (c.u + 0x7FFFu + ((c.u >> 16) & 1u)) >> 16;  // RNE
    return (short)r;
}
static __device__ __forceinline__ float bf2f(short s) {
    union { unsigned u; float f; } c; c.u = ((unsigned)(unsigned short)s) << 16;
    return c.f;
}
// truncating pack of two f32 into one u32 of 2 bf16 (lo = a, hi = b)
static __device__ __forceinline__ unsigned pack_trunc(float a, float b) {
    union { float f; unsigned u; } ca, cb; ca.f = a; cb.f = b;
    return (ca.u >> 16) | (cb.u & 0xFFFF0000u);
}

// ---------------------------------------------------------------------------
// Kernel 1: QKV projection. x:[B][C][N] f32 -> qT,kT:[B][N][C] bf16, vN:[B][C][N] bf16
// Grid (128, 3). Block 256 = 4 waves; wave owns 16 out-chans, thread 1 position.
// ---------------------------------------------------------------------------
__global__ __launch_bounds__(256) void qkv_proj(
    const float* __restrict__ x,
    const float* __restrict__ Wq, const float* __restrict__ bq,
    const float* __restrict__ Wk, const float* __restrict__ bk,
    const float* __restrict__ Wv, const float* __restrict__ bv,
    short* __restrict__ qT, short* __restrict__ kT, short* __restrict__ vN)
{
    int t    = threadIdx.x;
    int lane = t & 63;
    int wid  = __builtin_amdgcn_readfirstlane(t >> 6);   // 0..3
    int m    = blockIdx.y;                               // 0=q 1=k 2=v
    int och  = wid * 16;
    int pos  = blockIdx.x * 64 + lane;
    int b = pos >> 12;
    int n = pos & (NS - 1);

    const float* W    = (m == 0) ? Wq : (m == 1) ? Wk : Wv;
    const float* bias = (m == 0) ? bq : (m == 1) ? bk : bv;

    float acc[16];
    #pragma unroll
    for (int o = 0; o < 16; ++o) acc[o] = bias[och + o];

    const float* xb = x + (size_t)b * NC * NS + n;
    #pragma unroll 4
    for (int c = 0; c < NC; ++c) {
        float xv = xb[(size_t)c * NS];
        #pragma unroll
        for (int o = 0; o < 16; ++o)
            acc[o] = fmaf(W[(och + o) * NC + c], xv, acc[o]);
    }

    if (m < 2) {
        union U8 { bf16x8 v; short s[8]; } u0, u1;
        #pragma unroll
        for (int o = 0; o < 8; ++o) { u0.s[o] = f2bf(acc[o]); u1.s[o] = f2bf(acc[8 + o]); }
        short* dst = (m == 0 ? qT : kT) + ((size_t)b * NS + n) * NC + och;
        *(bf16x8*)dst       = u0.v;
        *(bf16x8*)(dst + 8) = u1.v;
    } else {
        #pragma unroll
        for (int o = 0; o < 16; ++o)
            vN[((size_t)b * NC + och + o) * NS + n] = f2bf(acc[o]);
    }
}

// ---------------------------------------------------------------------------
// Kernel 2: flash attention (R11 structure — best measured, simple 2-buffer).
// Block = 8 waves x 16 q-rows; grid (32, KS, 2). LDS-staged K/V (KVBLK=64),
// double-buffered global_load_lds(16B), XOR-swizzled source (m173).
// S^T = mfma(A=K,B=Q); P slot map == C/D map (zero-shuffle). T13 defer-max +
// truncating P->bf16 pack. Partials -> workspace.
// ---------------------------------------------------------------------------
__global__ __launch_bounds__(512) void flash_attn(
    const short* __restrict__ qT, const short* __restrict__ kT,
    const short* __restrict__ vN, short* __restrict__ Opart,
    float* __restrict__ Mpart, float* __restrict__ Lpart)
{
    int t = threadIdx.x;
    int wid  = t >> 6;
    int lane = t & 63;
    int r = lane & 15;      // query index within wave tile (col of S^T)
    int g = lane >> 4;      // lane group
    int qb = blockIdx.x;    // 0..31
    int ks = blockIdx.y;    // 0..KS-1
    int b  = blockIdx.z;    // 0..1
    int i0 = qb * 128 + wid * 16;

    __shared__ short sK[2][4096];   // [buf][64 rows x 64 ch], row-chunk swizzled
    __shared__ short sV[2][4096];

    const short* qbp = qT + (size_t)b * NS * NC;
    const short* kbp = kT + (size_t)b * NS * NC;
    const short* vbp = vN + (size_t)b * NC * NS;

    // Q fragments: B-operand, col = i0+r, k-slots c = 8g+s (+32)
    const bf16x8* qrow = (const bf16x8*)(qbp + (size_t)(i0 + r) * NC);
    bf16x8 qf0 = qrow[g];
    bf16x8 qf1 = qrow[4 + g];

    // staging indices (thread t covers 16B granule t of each tile)
    int rt = t >> 3;                       // row 0..63 (K: key row; V: channel)
    int cl = t & 7;                        // chunk 0..7
    int sw = ((cl ^ (rt & 7)) << 3);       // swizzled source chunk, in shorts
    const short* ks_base = kbp + (size_t)rt * NC + sw;   // + j0*NC
    const short* vs_base = vbp + (size_t)rt * NS + sw;   // + j0
    short* kdst = &sK[0][0] + ((t >> 6) << 9);  // wave-uniform base
    short* vdst = &sV[0][0] + ((t >> 6) << 9);

    int jbeg = ks * (NS / KS);

    // prologue: stage tile 0 into buf 0
    __builtin_amdgcn_global_load_lds((const void*)(ks_base + (size_t)jbeg * NC), (void*)kdst, 16, 0, 0);
    __builtin_amdgcn_global_load_lds((const void*)(vs_base + jbeg),              (void*)vdst, 16, 0, 0);
    __syncthreads();

    f32x4 o_acc[4];
    #pragma unroll
    for (int cc = 0; cc < 4; ++cc) o_acc[cc] = (f32x4){0.f, 0.f, 0.f, 0.f};
    float m_run = -__builtin_inff();
    float l_run = 0.f;

    int bufc = 0;
    for (int it = 0; it < NS / KS / 64; ++it) {
        if (it < NS / KS / 64 - 1) {
            int j1 = jbeg + (it + 1) * 64;
            __builtin_amdgcn_global_load_lds((const void*)(ks_base + (size_t)j1 * NC),
                                             (void*)(kdst + (bufc ^ 1) * 4096), 16, 0, 0);
            __builtin_amdgcn_global_load_lds((const void*)(vs_base + j1),
                                             (void*)(vdst + (bufc ^ 1) * 4096), 16, 0, 0);
        }
        const short* Kt = &sK[bufc][0];
        const short* Vt = &sV[bufc][0];

        // ---- S^T tiles: 4 j-chunks of 16 rows, operands from LDS (swizzled)
        f32x4 s[4];
        #pragma unroll
        for (int jj = 0; jj < 4; ++jj) {
            int row = jj * 16 + r;
            int rx = row & 7;
            bf16x8 ka  = *(const bf16x8*)(Kt + row * 64 + ((g ^ rx) << 3));
            bf16x8 kb2 = *(const bf16x8*)(Kt + row * 64 + (((4 + g) ^ rx) << 3));
            f32x4 acc = (f32x4){0.f, 0.f, 0.f, 0.f};
            acc = __builtin_amdgcn_mfma_f32_16x16x32_bf16(ka,  qf0, acc, 0, 0, 0);
            acc = __builtin_amdgcn_mfma_f32_16x16x32_bf16(kb2, qf1, acc, 0, 0, 0);
            s[jj] = acc;
        }
        // ---- online softmax (per q-row r; reduce over 4 g-groups)
        float pmax = -__builtin_inff();
        #pragma unroll
        for (int jj = 0; jj < 4; ++jj)
            #pragma unroll
            for (int e = 0; e < 4; ++e)
                pmax = fmaxf(pmax, s[jj][e]);
        pmax = fmaxf(pmax, __shfl_xor(pmax, 16));
        pmax = fmaxf(pmax, __shfl_xor(pmax, 32));

        // T13 defer-max
        if (!__all(pmax - m_run <= 8.f)) {
            float m_new = fmaxf(m_run, pmax);
            float alpha = __expf(m_run - m_new);
            m_run = m_new;
            l_run *= alpha;
            #pragma unroll
            for (int cc = 0; cc < 4; ++cc)
                #pragma unroll
                for (int e = 0; e < 4; ++e)
                    o_acc[cc][e] *= alpha;
        }

        float p[16];
        float lsum = 0.f;
        #pragma unroll
        for (int jj = 0; jj < 4; ++jj)
            #pragma unroll
            for (int e = 0; e < 4; ++e) {
                float pv = __expf(s[jj][e] - m_run);   // bounded by e^8
                p[jj * 4 + e] = pv;
                lsum += pv;
            }
        l_run += lsum;

        // ---- P fragments (truncating pack)
        union UP { u32x4 u; bf16x8 v; } pf0, pf1;
        #pragma unroll
        for (int e = 0; e < 4; ++e) {
            pf0.u[e] = pack_trunc(p[2 * e],     p[2 * e + 1]);
            pf1.u[e] = pack_trunc(p[8 + 2 * e], p[9 + 2 * e]);
        }
        // ---- PV: O^T[c][i] accumulate; V rows (channels) from LDS (swizzled)
        #pragma unroll
        for (int cc = 0; cc < 4; ++cc) {
            int row = cc * 16 + r;
            int rxs = (row & 7) << 3;
            const short* vr = Vt + row * 64;
            union UV { bf16x8 v; bf16x4 h[2]; };
            UV vf;
            vf.h[0] = *(const bf16x4*)(vr + ((4 * g) ^ rxs));
            vf.h[1] = *(const bf16x4*)(vr + ((4 * g + 16) ^ rxs));
            o_acc[cc] = __builtin_amdgcn_mfma_f32_16x16x32_bf16(vf.v, pf0.v, o_acc[cc], 0, 0, 0);
            vf.h[0] = *(const bf16x4*)(vr + ((4 * g + 32) ^ rxs));
            vf.h[1] = *(const bf16x4*)(vr + ((4 * g + 48) ^ rxs));
            o_acc[cc] = __builtin_amdgcn_mfma_f32_16x16x32_bf16(vf.v, pf1.v, o_acc[cc], 0, 0, 0);
        }
        __syncthreads();
        bufc ^= 1;
    }

    // ---- per-wave l total over the 4 disjoint lane-group partials
    float lt = l_run + __shfl_xor(l_run, 16);
    lt += __shfl_xor(lt, 32);

    // ---- write partials: O unnormalized (bf16), m, l (math exact for stale m)
    size_t pb = (size_t)(ks * NB + b);
    #pragma unroll
    for (int cc = 0; cc < 4; ++cc)
        #pragma unroll
        for (int e = 0; e < 4; ++e)
            Opart[(pb * NC + cc * 16 + g * 4 + e) * NS + i0 + r] = f2bf(o_acc[cc][e]);
    if (lane < 16) {
        Mpart[pb * NS + i0 + r] = m_run;
        Lpart[pb * NS + i0 + r] = lt;
    }
}

// ---------------------------------------------------------------------------
// Kernel 3: FUSED tail (cooperative): combine KS partials -> h (LDS only)
// -> out_proj + residual (y in REGISTERS) -> block group-stat partials
// -> grid.sync() -> stat totals -> GroupNorm + Swish -> out.
// Grid 128 x 256 thr (co-resident trivially). stats: [B][64 blk][32 g][2] f32.
// ---------------------------------------------------------------------------
__global__ __launch_bounds__(256) void fused_tail(
    const short* __restrict__ Opart, const float* __restrict__ Mpart,
    const float* __restrict__ Lpart, const float* __restrict__ x,
    const float* __restrict__ Wp, const float* __restrict__ bp,
    const float* __restrict__ gamma, const float* __restrict__ beta,
    float* __restrict__ stats, float* __restrict__ out)
{
    int t    = threadIdx.x;
    int lane = t & 63;
    int wid  = __builtin_amdgcn_readfirstlane(t >> 6);   // 0..3
    int c0   = wid * 16;
    int blk  = blockIdx.x;            // 0..127
    int pos  = blk * 64 + lane;
    int b    = pos >> 12;
    int n    = pos & (NS - 1);

    __shared__ float h_lds[64][65];   // [c][local n], +1 pad

    // ---- phase 1a: combine KS partials for channels c0..c0+15 at position n
    float mk[KS], lk[KS];
    #pragma unroll
    for (int k = 0; k < KS; ++k) {
        size_t pb = (size_t)(k * NB + b);
        mk[k] = Mpart[pb * NS + n];
        lk[k] = Lpart[pb * NS + n];
    }
    float Mt = mk[0];
    #pragma unroll
    for (int k = 1; k < KS; ++k) Mt = fmaxf(Mt, mk[k]);
    float a[KS];
    float Lt = 0.f;
    #pragma unroll
    for (int k = 0; k < KS; ++k) { a[k] = __expf(mk[k] - Mt); Lt += a[k] * lk[k]; }
    float invL = 1.f / Lt;
    #pragma unroll
    for (int o = 0; o < 16; ++o) {
        int c = c0 + o;
        float hv = 0.f;
        #pragma unroll
        for (int k = 0; k < KS; ++k)
            hv = fmaf(a[k], bf2f(Opart[((size_t)(k * NB + b) * NC + c) * NS + n]), hv);
        h_lds[c][lane] = hv * invL;
    }
    __syncthreads();

    // ---- phase 1b: out_proj + residual; y stays in registers
    float acc[16];
    #pragma unroll
    for (int o = 0; o < 16; ++o) acc[o] = bp[c0 + o];
    #pragma unroll 4
    for (int c = 0; c < NC; ++c) {
        float hv = h_lds[c][lane];
        #pragma unroll
        for (int o = 0; o < 16; ++o)
            acc[o] = fmaf(Wp[(c0 + o) * NC + c], hv, acc[o]);
    }
    const float* xb = x + (size_t)b * NC * NS + n;
    #pragma unroll
    for (int o = 0; o < 16; ++o)
        acc[o] += xb[(size_t)(c0 + o) * NS];

    // ---- phase 1c: per-block partial (sum, sumsq) for this wave's 8 groups
    float* st = stats + (((size_t)b * 64 + (blk & 63)) * 32) * 2;
    #pragma unroll
    for (int gq = 0; gq < 8; ++gq) {
        float s  = acc[2 * gq] + acc[2 * gq + 1];
        float s2 = acc[2 * gq] * acc[2 * gq] + acc[2 * gq + 1] * acc[2 * gq + 1];
        #pragma unroll
        for (int off = 32; off; off >>= 1) {
            s  += __shfl_xor(s, off);
            s2 += __shfl_xor(s2, off);
        }
        if (lane == 0) {
            st[(8 * wid + gq) * 2 + 0] = s;
            st[(8 * wid + gq) * 2 + 1] = s2;
        }
    }
    __threadfence();
    cg::this_grid().sync();

    // ---- phase 2: totals for this wave's 8 groups (lane l sums block l's slice)
    float mean_[8], rstd_[8];
    const float* sb = stats + ((size_t)b * 64 * 32) * 2;
    #pragma unroll
    for (int gq = 0; gq < 8; ++gq) {
        int g = 8 * wid + gq;
        float s  = sb[((size_t)lane * 32 + g) * 2 + 0];
        float s2 = sb[((size_t)lane * 32 + g) * 2 + 1];
        #pragma unroll
        for (int off = 32; off; off >>= 1) {
            s  += __shfl_xor(s, off);
            s2 += __shfl_xor(s2, off);
        }
        float mean = s * (1.f / 8192.f);
        float var  = s2 * (1.f / 8192.f) - mean * mean;
        mean_[gq] = mean;
        rstd_[gq] = rsqrtf(var + 1e-5f);
    }

    // ---- phase 3: normalize + affine + swish + store
    float* ob = out + (size_t)b * NC * NS + n;
    #pragma unroll
    for (int o = 0; o < 16; ++o) {
        int gq = o >> 1;
        float yn = (acc[o] - mean_[gq]) * rstd_[gq] * gamma[c0 + o] + beta[c0 + o];
        ob[(size_t)(c0 + o) * NS] = yn / (1.f + __expf(-yn));
    }
}

// ---------------------------------------------------------------------------
extern "C" void kernel_launch(void* const* d_in, const int* in_sizes, int n_in,
                              void* d_out, int out_size, void* d_ws, size_t ws_size,
                              hipStream_t stream)
{
    const float* x     = (const float*)d_in[0];
    const float* Wq    = (const float*)d_in[1];
    const float* bq    = (const float*)d_in[2];
    const float* Wk    = (const float*)d_in[3];
    const float* bk    = (const float*)d_in[4];
    const float* Wv    = (const float*)d_in[5];
    const float* bv    = (const float*)d_in[6];
    const float* Wp    = (const float*)d_in[7];
    const float* bp    = (const float*)d_in[8];
    const float* gamma = (const float*)d_in[9];
    const float* beta  = (const float*)d_in[10];
    float* out = (float*)d_out;

    char* ws = (char*)d_ws;
    short* qT    = (short*)(ws);                        // [B][N][C] bf16, 1 MB
    short* kT    = (short*)(ws + (1u << 20));           // [B][N][C] bf16, 1 MB
    short* vN    = (short*)(ws + (2u << 20));           // [B][C][N] bf16, 1 MB
    short* Opart = (short*)(ws + (3u << 20));           // [KS][B][C][N] bf16, 8 MB
    float* Mpart = (float*)(ws + (11u << 20));          // [KS][B][N] f32, 256 KB
    float* Lpart = (float*)(ws + (11u << 20) + (256u << 10)); // 256 KB
    float* stats = (float*)(ws + (12u << 20));          // [B][64][32][2] f32, 32 KB

    qkv_proj<<<dim3(128, 3), 256, 0, stream>>>(x, Wq, bq, Wk, bk, Wv, bv, qT, kT, vN);
    flash_attn<<<dim3(32, KS, 2), 512, 0, stream>>>(qT, kT, vN, Opart, Mpart, Lpart);

    void* args[] = { (void*)&Opart, (void*)&Mpart, (void*)&Lpart, (void*)&x,
                     (void*)&Wp, (void*)&bp, (void*)&gamma, (void*)&beta,
                     (void*)&stats, (void*)&out };
    hipLaunchCooperativeKernel((const void*)fused_tail, dim3(128), dim3(256),
                               args, 0, stream);
}

// Round 16
// 121.120 us; speedup vs baseline: 1.3909x; 1.3909x over previous
//
#include <hip/hip_runtime.h>
#include <hip/hip_bf16.h>

// Problem constants (B,C,D,H,W = 2,64,16,16,16)
#define NB 2
#define NC 64
#define NS 4096   // D*H*W
#define KS 8      // key-split factor (across blocks)

typedef __attribute__((ext_vector_type(8))) short bf16x8;
typedef __attribute__((ext_vector_type(4))) short bf16x4;
typedef __attribute__((ext_vector_type(4))) float f32x4;
typedef __attribute__((ext_vector_type(4))) float float4v;
typedef __attribute__((ext_vector_type(4))) unsigned int u32x4;

static __device__ __forceinline__ short f2bf(float f) {
    union { float f; unsigned u; } c; c.f = f;
    unsigned r = (c.u + 0x7FFFu + ((c.u >> 16) & 1u)) >> 16;  // RNE
    return (short)r;
}
static __device__ __forceinline__ float bf2f(short s) {
    union { unsigned u; float f; } c; c.u = ((unsigned)(unsigned short)s) << 16;
    return c.f;
}
// truncating pack of two f32 into one u32 of 2 bf16 (lo = a, hi = b)
static __device__ __forceinline__ unsigned pack_trunc(float a, float b) {
    union { float f; unsigned u; } ca, cb; ca.f = a; cb.f = b;
    return (ca.u >> 16) | (cb.u & 0xFFFF0000u);
}

// ---------------------------------------------------------------------------
// Kernel 1: QKV projection. x:[B][C][N] f32 -> qT,kT:[B][N][C] bf16, vN:[B][C][N] bf16
// Grid (128, 3). Block 256 = 4 waves; wave owns 16 out-chans, thread 1 position.
// ---------------------------------------------------------------------------
__global__ __launch_bounds__(256) void qkv_proj(
    const float* __restrict__ x,
    const float* __restrict__ Wq, const float* __restrict__ bq,
    const float* __restrict__ Wk, const float* __restrict__ bk,
    const float* __restrict__ Wv, const float* __restrict__ bv,
    short* __restrict__ qT, short* __restrict__ kT, short* __restrict__ vN)
{
    int t    = threadIdx.x;
    int lane = t & 63;
    int wid  = __builtin_amdgcn_readfirstlane(t >> 6);   // 0..3
    int m    = blockIdx.y;                               // 0=q 1=k 2=v
    int och  = wid * 16;
    int pos  = blockIdx.x * 64 + lane;
    int b = pos >> 12;
    int n = pos & (NS - 1);

    const float* W    = (m == 0) ? Wq : (m == 1) ? Wk : Wv;
    const float* bias = (m == 0) ? bq : (m == 1) ? bk : bv;

    float acc[16];
    #pragma unroll
    for (int o = 0; o < 16; ++o) acc[o] = bias[och + o];

    const float* xb = x + (size_t)b * NC * NS + n;
    #pragma unroll 4
    for (int c = 0; c < NC; ++c) {
        float xv = xb[(size_t)c * NS];
        #pragma unroll
        for (int o = 0; o < 16; ++o)
            acc[o] = fmaf(W[(och + o) * NC + c], xv, acc[o]);
    }

    if (m < 2) {
        union U8 { bf16x8 v; short s[8]; } u0, u1;
        #pragma unroll
        for (int o = 0; o < 8; ++o) { u0.s[o] = f2bf(acc[o]); u1.s[o] = f2bf(acc[8 + o]); }
        short* dst = (m == 0 ? qT : kT) + ((size_t)b * NS + n) * NC + och;
        *(bf16x8*)dst       = u0.v;
        *(bf16x8*)(dst + 8) = u1.v;
    } else {
        #pragma unroll
        for (int o = 0; o < 16; ++o)
            vN[((size_t)b * NC + och + o) * NS + n] = f2bf(acc[o]);
    }
}

// ---------------------------------------------------------------------------
// Kernel 2: flash attention (R11-measured structure, simple 2-buffer).
// Block = 8 waves x 16 q-rows; grid (32, KS, 2). LDS-staged K/V (KVBLK=64),
// double-buffered global_load_lds(16B), XOR-swizzled source (m173).
// S^T = mfma(A=K,B=Q); P slot map == C/D map (zero-shuffle). T13 defer-max +
// truncating P->bf16 pack. Partials -> workspace.
// ---------------------------------------------------------------------------
__global__ __launch_bounds__(512) void flash_attn(
    const short* __restrict__ qT, const short* __restrict__ kT,
    const short* __restrict__ vN, short* __restrict__ Opart,
    float* __restrict__ Mpart, float* __restrict__ Lpart)
{
    int t = threadIdx.x;
    int wid  = t >> 6;
    int lane = t & 63;
    int r = lane & 15;      // query index within wave tile (col of S^T)
    int g = lane >> 4;      // lane group
    int qb = blockIdx.x;    // 0..31
    int ks = blockIdx.y;    // 0..KS-1
    int b  = blockIdx.z;    // 0..1
    int i0 = qb * 128 + wid * 16;

    __shared__ short sK[2][4096];   // [buf][64 rows x 64 ch], row-chunk swizzled
    __shared__ short sV[2][4096];

    const short* qbp = qT + (size_t)b * NS * NC;
    const short* kbp = kT + (size_t)b * NS * NC;
    const short* vbp = vN + (size_t)b * NC * NS;

    // Q fragments: B-operand, col = i0+r, k-slots c = 8g+s (+32)
    const bf16x8* qrow = (const bf16x8*)(qbp + (size_t)(i0 + r) * NC);
    bf16x8 qf0 = qrow[g];
    bf16x8 qf1 = qrow[4 + g];

    // staging indices (thread t covers 16B granule t of each tile)
    int rt = t >> 3;                       // row 0..63 (K: key row; V: channel)
    int cl = t & 7;                        // chunk 0..7
    int sw = ((cl ^ (rt & 7)) << 3);       // swizzled source chunk, in shorts
    const short* ks_base = kbp + (size_t)rt * NC + sw;   // + j0*NC
    const short* vs_base = vbp + (size_t)rt * NS + sw;   // + j0
    short* kdst = &sK[0][0] + ((t >> 6) << 9);  // wave-uniform base
    short* vdst = &sV[0][0] + ((t >> 6) << 9);

    int jbeg = ks * (NS / KS);

    // prologue: stage tile 0 into buf 0
    __builtin_amdgcn_global_load_lds((const void*)(ks_base + (size_t)jbeg * NC), (void*)kdst, 16, 0, 0);
    __builtin_amdgcn_global_load_lds((const void*)(vs_base + jbeg),              (void*)vdst, 16, 0, 0);
    __syncthreads();

    f32x4 o_acc[4];
    #pragma unroll
    for (int cc = 0; cc < 4; ++cc) o_acc[cc] = (f32x4){0.f, 0.f, 0.f, 0.f};
    float m_run = -__builtin_inff();
    float l_run = 0.f;

    int bufc = 0;
    for (int it = 0; it < NS / KS / 64; ++it) {
        if (it < NS / KS / 64 - 1) {
            int j1 = jbeg + (it + 1) * 64;
            __builtin_amdgcn_global_load_lds((const void*)(ks_base + (size_t)j1 * NC),
                                             (void*)(kdst + (bufc ^ 1) * 4096), 16, 0, 0);
            __builtin_amdgcn_global_load_lds((const void*)(vs_base + j1),
                                             (void*)(vdst + (bufc ^ 1) * 4096), 16, 0, 0);
        }
        const short* Kt = &sK[bufc][0];
        const short* Vt = &sV[bufc][0];

        // ---- S^T tiles: 4 j-chunks of 16 rows, operands from LDS (swizzled)
        f32x4 s[4];
        #pragma unroll
        for (int jj = 0; jj < 4; ++jj) {
            int row = jj * 16 + r;
            int rx = row & 7;
            bf16x8 ka  = *(const bf16x8*)(Kt + row * 64 + ((g ^ rx) << 3));
            bf16x8 kb2 = *(const bf16x8*)(Kt + row * 64 + (((4 + g) ^ rx) << 3));
            f32x4 acc = (f32x4){0.f, 0.f, 0.f, 0.f};
            acc = __builtin_amdgcn_mfma_f32_16x16x32_bf16(ka,  qf0, acc, 0, 0, 0);
            acc = __builtin_amdgcn_mfma_f32_16x16x32_bf16(kb2, qf1, acc, 0, 0, 0);
            s[jj] = acc;
        }
        // ---- online softmax (per q-row r; reduce over 4 g-groups)
        float pmax = -__builtin_inff();
        #pragma unroll
        for (int jj = 0; jj < 4; ++jj)
            #pragma unroll
            for (int e = 0; e < 4; ++e)
                pmax = fmaxf(pmax, s[jj][e]);
        pmax = fmaxf(pmax, __shfl_xor(pmax, 16));
        pmax = fmaxf(pmax, __shfl_xor(pmax, 32));

        // T13 defer-max
        if (!__all(pmax - m_run <= 8.f)) {
            float m_new = fmaxf(m_run, pmax);
            float alpha = __expf(m_run - m_new);
            m_run = m_new;
            l_run *= alpha;
            #pragma unroll
            for (int cc = 0; cc < 4; ++cc)
                #pragma unroll
                for (int e = 0; e < 4; ++e)
                    o_acc[cc][e] *= alpha;
        }

        float p[16];
        float lsum = 0.f;
        #pragma unroll
        for (int jj = 0; jj < 4; ++jj)
            #pragma unroll
            for (int e = 0; e < 4; ++e) {
                float pv = __expf(s[jj][e] - m_run);   // bounded by e^8
                p[jj * 4 + e] = pv;
                lsum += pv;
            }
        l_run += lsum;

        // ---- P fragments (truncating pack)
        union UP { u32x4 u; bf16x8 v; } pf0, pf1;
        #pragma unroll
        for (int e = 0; e < 4; ++e) {
            pf0.u[e] = pack_trunc(p[2 * e],     p[2 * e + 1]);
            pf1.u[e] = pack_trunc(p[8 + 2 * e], p[9 + 2 * e]);
        }
        // ---- PV: O^T[c][i] accumulate; V rows (channels) from LDS (swizzled)
        #pragma unroll
        for (int cc = 0; cc < 4; ++cc) {
            int row = cc * 16 + r;
            int rxs = (row & 7) << 3;
            const short* vr = Vt + row * 64;
            union UV { bf16x8 v; bf16x4 h[2]; };
            UV vf;
            vf.h[0] = *(const bf16x4*)(vr + ((4 * g) ^ rxs));
            vf.h[1] = *(const bf16x4*)(vr + ((4 * g + 16) ^ rxs));
            o_acc[cc] = __builtin_amdgcn_mfma_f32_16x16x32_bf16(vf.v, pf0.v, o_acc[cc], 0, 0, 0);
            vf.h[0] = *(const bf16x4*)(vr + ((4 * g + 32) ^ rxs));
            vf.h[1] = *(const bf16x4*)(vr + ((4 * g + 48) ^ rxs));
            o_acc[cc] = __builtin_amdgcn_mfma_f32_16x16x32_bf16(vf.v, pf1.v, o_acc[cc], 0, 0, 0);
        }
        __syncthreads();
        bufc ^= 1;
    }

    // ---- per-wave l total over the 4 disjoint lane-group partials
    float lt = l_run + __shfl_xor(l_run, 16);
    lt += __shfl_xor(lt, 32);

    // ---- write partials: O unnormalized (bf16), m, l (math exact for stale m)
    size_t pb = (size_t)(ks * NB + b);
    #pragma unroll
    for (int cc = 0; cc < 4; ++cc)
        #pragma unroll
        for (int e = 0; e < 4; ++e)
            Opart[(pb * NC + cc * 16 + g * 4 + e) * NS + i0 + r] = f2bf(o_acc[cc][e]);
    if (lane < 16) {
        Mpart[pb * NS + i0 + r] = m_run;
        Lpart[pb * NS + i0 + r] = lt;
    }
}

// ---------------------------------------------------------------------------
// Kernel 3: fused mid (ordinary launch): combine KS partials -> h (LDS only)
// -> out_proj + residual -> y (f32) + per-block GroupNorm stat partials.
// Grid 128 x 256 thr. stats: [B][64 blk][32 g][2] f32 (32 KB).
// (Phases 1a/1b identical to R15's correctness-proven fused_tail.)
// ---------------------------------------------------------------------------
__global__ __launch_bounds__(256) void fused_mid(
    const short* __restrict__ Opart, const float* __restrict__ Mpart,
    const float* __restrict__ Lpart, const float* __restrict__ x,
    const float* __restrict__ Wp, const float* __restrict__ bp,
    float* __restrict__ y, float* __restrict__ stats)
{
    int t    = threadIdx.x;
    int lane = t & 63;
    int wid  = __builtin_amdgcn_readfirstlane(t >> 6);   // 0..3
    int c0   = wid * 16;
    int blk  = blockIdx.x;            // 0..127
    int pos  = blk * 64 + lane;
    int b    = pos >> 12;
    int n    = pos & (NS - 1);

    __shared__ float h_lds[64][65];   // [c][local n], +1 pad

    // ---- phase 1a: combine KS partials for channels c0..c0+15 at position n
    float mk[KS], lk[KS];
    #pragma unroll
    for (int k = 0; k < KS; ++k) {
        size_t pb = (size_t)(k * NB + b);
        mk[k] = Mpart[pb * NS + n];
        lk[k] = Lpart[pb * NS + n];
    }
    float Mt = mk[0];
    #pragma unroll
    for (int k = 1; k < KS; ++k) Mt = fmaxf(Mt, mk[k]);
    float a[KS];
    float Lt = 0.f;
    #pragma unroll
    for (int k = 0; k < KS; ++k) { a[k] = __expf(mk[k] - Mt); Lt += a[k] * lk[k]; }
    float invL = 1.f / Lt;
    #pragma unroll
    for (int o = 0; o < 16; ++o) {
        int c = c0 + o;
        float hv = 0.f;
        #pragma unroll
        for (int k = 0; k < KS; ++k)
            hv = fmaf(a[k], bf2f(Opart[((size_t)(k * NB + b) * NC + c) * NS + n]), hv);
        h_lds[c][lane] = hv * invL;
    }
    __syncthreads();

    // ---- phase 1b: out_proj + residual -> y
    float acc[16];
    #pragma unroll
    for (int o = 0; o < 16; ++o) acc[o] = bp[c0 + o];
    #pragma unroll 4
    for (int c = 0; c < NC; ++c) {
        float hv = h_lds[c][lane];
        #pragma unroll
        for (int o = 0; o < 16; ++o)
            acc[o] = fmaf(Wp[(c0 + o) * NC + c], hv, acc[o]);
    }
    const float* xb = x + (size_t)b * NC * NS + n;
    float* yb = y + (size_t)b * NC * NS + n;
    #pragma unroll
    for (int o = 0; o < 16; ++o) {
        acc[o] += xb[(size_t)(c0 + o) * NS];
        yb[(size_t)(c0 + o) * NS] = acc[o];
    }

    // ---- phase 1c: per-block partial (sum, sumsq) for this wave's 8 groups
    float* st = stats + (((size_t)b * 64 + (blk & 63)) * 32) * 2;
    #pragma unroll
    for (int gq = 0; gq < 8; ++gq) {
        float s  = acc[2 * gq] + acc[2 * gq + 1];
        float s2 = acc[2 * gq] * acc[2 * gq] + acc[2 * gq + 1] * acc[2 * gq + 1];
        #pragma unroll
        for (int off = 32; off; off >>= 1) {
            s  += __shfl_xor(s, off);
            s2 += __shfl_xor(s2, off);
        }
        if (lane == 0) {
            st[(8 * wid + gq) * 2 + 0] = s;
            st[(8 * wid + gq) * 2 + 1] = s2;
        }
    }
}

// ---------------------------------------------------------------------------
// Kernel 4: GroupNorm finalize + Swish. One block of 1024 thr per (b, group).
// mean/rstd from the 64 block partials (no y re-reduction); then 8 elems/thr.
// ---------------------------------------------------------------------------
__global__ __launch_bounds__(1024) void gnorm_final(
    const float* __restrict__ y, const float* __restrict__ stats,
    const float* __restrict__ gamma, const float* __restrict__ beta,
    float* __restrict__ out)
{
    int t  = threadIdx.x;
    int bg = blockIdx.x;              // 0..63
    int b  = bg >> 5;
    int gr = bg & 31;
    int lane = t & 63;
    size_t base = ((size_t)b * NC + gr * 2) * NS;

    // totals from 64 block partials (each lane loads one block's slice)
    const float* sb = stats + ((size_t)b * 64 * 32) * 2;
    float s  = sb[((size_t)lane * 32 + gr) * 2 + 0];
    float s2 = sb[((size_t)lane * 32 + gr) * 2 + 1];
    #pragma unroll
    for (int off = 32; off; off >>= 1) {
        s  += __shfl_xor(s, off);
        s2 += __shfl_xor(s2, off);
    }
    float mean = s * (1.f / 8192.f);
    float var  = s2 * (1.f / 8192.f) - mean * mean;
    float rstd = rsqrtf(var + 1e-5f);

    float4v v0 = *(const float4v*)(y + base + t * 8);
    float4v v1 = *(const float4v*)(y + base + t * 8 + 4);
    float gg = (t < 512) ? gamma[gr * 2] : gamma[gr * 2 + 1];
    float bb = (t < 512) ? beta[gr * 2]  : beta[gr * 2 + 1];
    float4v o0, o1;
    #pragma unroll
    for (int i = 0; i < 4; ++i) {
        float yn = (v0[i] - mean) * rstd * gg + bb;
        o0[i] = yn / (1.f + __expf(-yn));
        float yn1 = (v1[i] - mean) * rstd * gg + bb;
        o1[i] = yn1 / (1.f + __expf(-yn1));
    }
    *(float4v*)(out + base + t * 8)     = o0;
    *(float4v*)(out + base + t * 8 + 4) = o1;
}

// ---------------------------------------------------------------------------
extern "C" void kernel_launch(void* const* d_in, const int* in_sizes, int n_in,
                              void* d_out, int out_size, void* d_ws, size_t ws_size,
                              hipStream_t stream)
{
    const float* x     = (const float*)d_in[0];
    const float* Wq    = (const float*)d_in[1];
    const float* bq    = (const float*)d_in[2];
    const float* Wk    = (const float*)d_in[3];
    const float* bk    = (const float*)d_in[4];
    const float* Wv    = (const float*)d_in[5];
    const float* bv    = (const float*)d_in[6];
    const float* Wp    = (const float*)d_in[7];
    const float* bp    = (const float*)d_in[8];
    const float* gamma = (const float*)d_in[9];
    const float* beta  = (const float*)d_in[10];
    float* out = (float*)d_out;

    char* ws = (char*)d_ws;
    short* qT    = (short*)(ws);                        // [B][N][C] bf16, 1 MB
    short* kT    = (short*)(ws + (1u << 20));           // [B][N][C] bf16, 1 MB
    short* vN    = (short*)(ws + (2u << 20));           // [B][C][N] bf16, 1 MB
    short* Opart = (short*)(ws + (3u << 20));           // [KS][B][C][N] bf16, 8 MB
    float* Mpart = (float*)(ws + (11u << 20));          // [KS][B][N] f32, 256 KB
    float* Lpart = (float*)(ws + (11u << 20) + (256u << 10)); // 256 KB
    float* stats = (float*)(ws + (12u << 20));          // [B][64][32][2] f32, 32 KB
    float* y     = (float*)(ws + (13u << 20));          // [B][C][N] f32, 2 MB

    qkv_proj<<<dim3(128, 3), 256, 0, stream>>>(x, Wq, bq, Wk, bk, Wv, bv, qT, kT, vN);
    flash_attn<<<dim3(32, KS, 2), 512, 0, stream>>>(qT, kT, vN, Opart, Mpart, Lpart);
    fused_mid<<<128, 256, 0, stream>>>(Opart, Mpart, Lpart, x, Wp, bp, y, stats);
    gnorm_final<<<64, 1024, 0, stream>>>(y, stats, gamma, beta, out);
}